// Round 4
// baseline (274.817 us; speedup 1.0000x reference)
//
#include <hip/hip_runtime.h>

#define TAU 0.02f

constexpr int Bc = 8, Cc = 64, Hc = 256, Wc = 256;
constexpr int R  = 32;   // output rows per tile
constexpr int NR = 40;   // staged rows; 40*256*4 = 40960 B -> 4 blocks/CU

__device__ __forceinline__ void coordf(float g, float shift, int n,
                                       int& i0, int& i1, float& w) {
    // exact reference semantics
    float p = (g + shift + 1.0f) * (0.5f * (float)(n - 1));
    p = fminf(fmaxf(p, 0.0f), (float)(n - 1));
    float f = floorf(p);
    w  = p - f;
    i0 = (int)f;
    i1 = min(i0 + 1, n - 1);
}

// clamp-adjusted pair: taps always (m, m+1); weight 1.0 when i0 was clamped to n-1.
// lerp(t[m], t[m+1], w') == reference value to ~1 ulp (bilinear continuity).
__device__ __forceinline__ void coord_adj(float g, float shift, int n,
                                          int& m, float& w) {
    int i0, i1; float ww;
    coordf(g, shift, n, i0, i1, ww);
    const bool top = (i0 == n - 1);
    m = top ? n - 2 : i0;
    w = top ? 1.0f  : ww;
}

__device__ __forceinline__ float gy_of(int i) {
    // analytic linspace(-1,1,H); validated in rounds 2-3
    return fmaf((float)i, 2.0f / 255.0f, -1.0f);
}

__device__ __forceinline__ float rdlane_f(float v, int lane) {
    return __int_as_float(__builtin_amdgcn_readlane(__float_as_int(v), lane));
}

__global__ __launch_bounds__(256, 4) void remizov_rl(
    const float* __restrict__ x,
    const float* __restrict__ th_a,
    const float* __restrict__ th_bx,
    const float* __restrict__ th_by,
    const float* __restrict__ th_c,
    const float* __restrict__ base_gx,
    const float* __restrict__ base_gy,
    float* __restrict__ out)
{
    __shared__ float tile[NR * Wc];   // exactly 40 KB

    const int j  = threadIdx.x;
    const int i0 = blockIdx.x * R;
    const int c  = blockIdx.y;
    const int b  = blockIdx.z;

    // ---- per-channel constants ----
    const float a  = log1pf(expf(th_a[c]));   // softplus
    const float s  = sqrtf(a * TAU + 1e-8f);
    const float dx = th_bx[c] * TAU;
    const float dy = th_by[c] * TAU;
    const float tc = th_c[c]  * TAU;

    // ---- per-lane y metadata: lane (j&31) owns output row i0+(j&31) ----
    int   m_yc, m_yp, m_yn;
    float m_wc, m_wp, m_wn;
    {
        const float gyr = gy_of(i0 + (j & 31));
        coord_adj(gyr,      dy, Hc, m_yc, m_wc);
        coord_adj(gyr,  s + dy, Hc, m_yp, m_wp);
        coord_adj(gyr, -s + dy, Hc, m_yn, m_wn);
    }

    // ---- staged window from lane 0 (min) / lane 31 (max); coord map monotone in i ----
    int rlo = min(i0, min(min(__builtin_amdgcn_readlane(m_yc, 0),
                              __builtin_amdgcn_readlane(m_yp, 0)),
                              __builtin_amdgcn_readlane(m_yn, 0)));
    int rhi = max(i0 + R - 1, max(max(__builtin_amdgcn_readlane(m_yc, 31),
                                      __builtin_amdgcn_readlane(m_yp, 31)),
                                      __builtin_amdgcn_readlane(m_yn, 31)) + 1);
    const int nrows = rhi - rlo + 1;

    // ---- x metadata: row-invariant, clamp-adjusted contiguous pairs ----
    const float gxv = base_gx[j];
    int xp, xn, xc; float wxp, wxn, wxc;
    coord_adj(gxv,  s + dx, Wc, xp, wxp);
    coord_adj(gxv, -s + dx, Wc, xn, wxn);
    coord_adj(gxv,      dx, Wc, xc, wxc);

    const size_t plane = (size_t)(b * Cc + c) * (size_t)(Hc * Wc);
    float* __restrict__ dst = out + plane + (size_t)i0 * Wc + j;

    if (nrows > NR) {
        // ---- fallback: direct-global path (needs shift > 4 px; ~10 sigma) ----
        const float* __restrict__ P = x + plane;
        for (int r = 0; r < R; ++r) {
            const float gyr = gy_of(i0 + r);
            int yc, yp, yn; float wyc, wyp, wyn;
            coord_adj(gyr,      dy, Hc, yc, wyc);
            coord_adj(gyr,  s + dy, Hc, yp, wyp);
            coord_adj(gyr, -s + dy, Hc, yn, wyn);
            auto bilg = [&](int y0, float wy, int x0, float wx) -> float {
                const float* r0 = P + y0 * Wc;
                const float* r1 = r0 + Wc;
                float t0 = r0[x0] + wx * (r0[x0 + 1] - r0[x0]);
                float t1 = r1[x0] + wx * (r1[x0 + 1] - r1[x0]);
                return t0 + wy * (t1 - t0);
            };
            float v0 = bilg(yc, wyc, xp, wxp);
            float v1 = bilg(yc, wyc, xn, wxn);
            float v2 = bilg(yp, wyp, xc, wxc);
            float v3 = bilg(yn, wyn, xc, wxc);
            float xv = P[(i0 + r) * Wc + j];
            dst[r * Wc] = 0.25f * (v0 + v1 + v2 + v3) + tc * xv;
        }
        return;
    }

    // ---- stage contiguous row window: coalesced float4 copy ----
    {
        const float* __restrict__ src = x + plane + (size_t)rlo * Wc;
        const int total = nrows * Wc;
        for (int e = j * 4; e < total; e += 256 * 4) {
            *reinterpret_cast<float4*>(&tile[e]) =
                *reinterpret_cast<const float4*>(src + e);
        }
    }
    __syncthreads();

    // horizontal lerp: two adjacent dwords -> one ds_read2_b32
    auto Hl = [&](int rowf, int xm, float wx) -> float {
        float t0 = tile[rowf + xm];
        float t1 = tile[rowf + xm + 1];
        return t0 + wx * (t1 - t0);
    };

    const int xvbase = (i0 - rlo) * Wc + j;
    int pyc = -1000000, pyp = -1000000, pyn = -1000000;
    float A0 = 0, A1 = 0, B0 = 0, B1 = 0, C0 = 0, C1 = 0, D0 = 0, D1 = 0;

#pragma unroll
    for (int r = 0; r < R; ++r) {
        // scalar (SGPR) y metadata via readlane — uniform across the wave
        const int   yc  = __builtin_amdgcn_readlane(m_yc, r);
        const float wyc = rdlane_f(m_wc, r);
        const int   yp  = __builtin_amdgcn_readlane(m_yp, r);
        const float wyp = rdlane_f(m_wp, r);
        const int   yn  = __builtin_amdgcn_readlane(m_yn, r);
        const float wyn = rdlane_f(m_wn, r);

        const int bc = (yc - rlo) << 8;   // tile row base (floats)
        if (yc == pyc + 1) {
            A0 = A1; B0 = B1;
            A1 = Hl(bc + Wc, xp, wxp);
            B1 = Hl(bc + Wc, xn, wxn);
        } else if (yc != pyc) {
            A0 = Hl(bc,      xp, wxp); A1 = Hl(bc + Wc, xp, wxp);
            B0 = Hl(bc,      xn, wxn); B1 = Hl(bc + Wc, xn, wxn);
        }
        pyc = yc;

        const int bp = (yp - rlo) << 8;
        if (yp == pyp + 1) {
            C0 = C1; C1 = Hl(bp + Wc, xc, wxc);
        } else if (yp != pyp) {
            C0 = Hl(bp, xc, wxc); C1 = Hl(bp + Wc, xc, wxc);
        }
        pyp = yp;

        const int bn = (yn - rlo) << 8;
        if (yn == pyn + 1) {
            D0 = D1; D1 = Hl(bn + Wc, xc, wxc);
        } else if (yn != pyn) {
            D0 = Hl(bn, xc, wxc); D1 = Hl(bn + Wc, xc, wxc);
        }
        pyn = yn;

        const float v01 = (A0 + wyc * (A1 - A0)) + (B0 + wyc * (B1 - B0));
        const float v2  = C0 + wyp * (C1 - C0);
        const float v3  = D0 + wyn * (D1 - D0);
        const float xv  = tile[xvbase + (r << 8)];
        dst[(size_t)(r << 8)] = 0.25f * (v01 + v2 + v3) + tc * xv;
    }
}

extern "C" void kernel_launch(void* const* d_in, const int* in_sizes, int n_in,
                              void* d_out, int out_size, void* d_ws, size_t ws_size,
                              hipStream_t stream)
{
    const float* x       = (const float*)d_in[0];
    const float* th_a    = (const float*)d_in[1];
    const float* th_bx   = (const float*)d_in[2];
    const float* th_by   = (const float*)d_in[3];
    const float* th_c    = (const float*)d_in[4];
    const float* base_gx = (const float*)d_in[5];
    const float* base_gy = (const float*)d_in[6];
    float* out = (float*)d_out;

    dim3 grid(Hc / R, Cc, Bc);
    dim3 block(Wc);
    remizov_rl<<<grid, block, 0, stream>>>(x, th_a, th_bx, th_by, th_c,
                                           base_gx, base_gy, out);
}

// Round 5
// 255.355 us; speedup vs baseline: 1.0762x; 1.0762x over previous
//
#include <hip/hip_runtime.h>

#define TAU 0.02f

constexpr int Bc = 8, Cc = 64, Hc = 256, Wc = 256;
constexpr int R  = 32;   // output rows per tile
constexpr int NR = 40;   // staged rows; 40*256*4 = 40960 B -> 4 blocks/CU

__device__ __forceinline__ void coordf(float g, float shift, int n,
                                       int& i0, int& i1, float& w) {
    // exact reference semantics
    float p = (g + shift + 1.0f) * (0.5f * (float)(n - 1));
    p = fminf(fmaxf(p, 0.0f), (float)(n - 1));
    float f = floorf(p);
    w  = p - f;
    i0 = (int)f;
    i1 = min(i0 + 1, n - 1);
}

// clamp-adjusted pair: taps always (m, m+1); weight 1.0 when i0 clamped to n-1.
__device__ __forceinline__ void coord_adj(float g, float shift, int n,
                                          int& m, float& w) {
    int i0, i1; float ww;
    coordf(g, shift, n, i0, i1, ww);
    const bool top = (i0 == n - 1);
    m = top ? n - 2 : i0;
    w = top ? 1.0f  : ww;
}

__device__ __forceinline__ float gy_of(int i) {
    return fmaf((float)i, 2.0f / 255.0f, -1.0f);   // validated rounds 2-4
}

__device__ __forceinline__ float rdlane_f(float v, int lane) {
    return __int_as_float(__builtin_amdgcn_readlane(__float_as_int(v), lane));
}

__global__ __launch_bounds__(256, 4) void remizov_sten(
    const float* __restrict__ x,
    const float* __restrict__ th_a,
    const float* __restrict__ th_bx,
    const float* __restrict__ th_by,
    const float* __restrict__ th_c,
    const float* __restrict__ base_gx,
    const float* __restrict__ base_gy,
    float* __restrict__ out)
{
    __shared__ float tile[NR * Wc];   // exactly 40 KB

    const int j  = threadIdx.x;
    const int i0 = blockIdx.x * R;
    const int c  = blockIdx.y;
    const int b  = blockIdx.z;

    // ---- per-channel constants ----
    const float a  = log1pf(expf(th_a[c]));   // softplus
    const float s  = sqrtf(a * TAU + 1e-8f);
    const float dx = th_bx[c] * TAU;
    const float dy = th_by[c] * TAU;
    const float tc = th_c[c]  * TAU;

    // ---- per-lane exact y metadata: lane (j&31) owns output row i0+(j&31) ----
    int   m_yc, m_yp, m_yn;
    float m_wc, m_wp, m_wn;
    {
        const float gyr = gy_of(i0 + (j & 31));
        coord_adj(gyr,      dy, Hc, m_yc, m_wc);
        coord_adj(gyr,  s + dy, Hc, m_yp, m_wp);
        coord_adj(gyr, -s + dy, Hc, m_yn, m_wn);
    }

    // ---- staged window (coord map monotone in i) ----
    int rlo = min(i0, min(min(__builtin_amdgcn_readlane(m_yc, 0),
                              __builtin_amdgcn_readlane(m_yp, 0)),
                              __builtin_amdgcn_readlane(m_yn, 0)));
    int rhi = max(i0 + R - 1, max(max(__builtin_amdgcn_readlane(m_yc, 31),
                                      __builtin_amdgcn_readlane(m_yp, 31)),
                                      __builtin_amdgcn_readlane(m_yn, 31)) + 1);
    const int nrows = rhi - rlo + 1;

    // ---- x metadata: row-invariant, clamp-adjusted contiguous pairs ----
    const float gxv = base_gx[j];
    int xp, xn, xc; float wxp, wxn, wxc;
    coord_adj(gxv,  s + dx, Wc, xp, wxp);
    coord_adj(gxv, -s + dx, Wc, xn, wxn);
    coord_adj(gxv,      dx, Wc, xc, wxc);

    const size_t plane = (size_t)(b * Cc + c) * (size_t)(Hc * Wc);
    float* __restrict__ dst = out + plane + (size_t)i0 * Wc + j;

    if (nrows > NR) {
        // ---- fallback: direct-global (shift > 4 px; ~10 sigma, never in practice) ----
        const float* __restrict__ P = x + plane;
        for (int r = 0; r < R; ++r) {
            const float gyr = gy_of(i0 + r);
            int yc, yp, yn; float wyc, wyp, wyn;
            coord_adj(gyr,      dy, Hc, yc, wyc);
            coord_adj(gyr,  s + dy, Hc, yp, wyp);
            coord_adj(gyr, -s + dy, Hc, yn, wyn);
            auto bilg = [&](int y0, float wy, int x0, float wx) -> float {
                const float* r0 = P + y0 * Wc;
                const float* r1 = r0 + Wc;
                float t0 = r0[x0] + wx * (r0[x0 + 1] - r0[x0]);
                float t1 = r1[x0] + wx * (r1[x0 + 1] - r1[x0]);
                return t0 + wy * (t1 - t0);
            };
            float v0 = bilg(yc, wyc, xp, wxp);
            float v1 = bilg(yc, wyc, xn, wxn);
            float v2 = bilg(yp, wyp, xc, wxc);
            float v3 = bilg(yn, wyn, xc, wxc);
            float xv = P[(i0 + r) * Wc + j];
            dst[r * Wc] = 0.25f * (v0 + v1 + v2 + v3) + tc * xv;
        }
        return;
    }

    // ---- stage contiguous row window: coalesced float4 copy ----
    {
        const float* __restrict__ src = x + plane + (size_t)rlo * Wc;
        const int total = nrows * Wc;
        for (int e = j * 4; e < total; e += 256 * 4) {
            *reinterpret_cast<float4*>(&tile[e]) =
                *reinterpret_cast<const float4*>(src + e);
        }
    }
    __syncthreads();

    // ---- uniform-stencil parameters from lane 16 ----
    const int acr = __builtin_amdgcn_readlane(m_yc, 16) - (i0 + 16);
    const int apr = __builtin_amdgcn_readlane(m_yp, 16) - (i0 + 16);
    const int anr = __builtin_amdgcn_readlane(m_yn, 16) - (i0 + 16);
    const float wc = rdlane_f(m_wc, 16);
    const float wp = rdlane_f(m_wp, 16);
    const float wn = rdlane_f(m_wn, 16);

    // per-row eligibility mask (bit r = row i0+r conforms to the uniform stencil)
    unsigned int mask;
    {
        const int lane = j & 31;
        bool ok = (m_yc == i0 + lane + acr) &&
                  (m_yp == i0 + lane + apr) &&
                  (m_yn == i0 + lane + anr);
        mask = (unsigned int)__ballot(ok);   // lanes 32..63 mirror lanes 0..31
        if (acr < -1 || acr > 0 || apr > 3 || apr < -4 || anr < -4 || anr > 3)
            mask = 0u;                       // outside supported window
    }

    // ---- block-constant stencil coefficients (scalar) ----
    float cA[3], cB[9];
#pragma unroll
    for (int k = 0; k < 3; ++k)
        cA[k] = ((k == acr + 1) ? (1.0f - wc) : 0.0f) +
                ((k == acr + 2) ? wc          : 0.0f);
#pragma unroll
    for (int k = 0; k < 9; ++k)
        cB[k] = ((k == apr + 4) ? (1.0f - wp) : 0.0f) +
                ((k == apr + 5) ? wp          : 0.0f) +
                ((k == anr + 4) ? (1.0f - wn) : 0.0f) +
                ((k == anr + 5) ? wn          : 0.0f);

    // horizontal lerp at staged row (row index clamped; one ds_read2_b32)
    auto ldH = [&](int row, int xm, float wx) -> float {
        row = min(max(row, rlo), rhi);
        const int base = (row - rlo) << 8;
        float t0 = tile[base + xm], t1 = tile[base + xm + 1];
        return t0 + wx * (t1 - t0);
    };
    auto ldS = [&](int row) -> float {        // h+ + h-  (two ds_read2)
        return ldH(row, xp, wxp) + ldH(row, xn, wxn);
    };

    // ---- rolling register windows, centered at output row i = i0+r ----
    float S0 = ldS(i0 - 1), S1 = ldS(i0), S2 = ldS(i0 + 1);
    float W0 = ldH(i0 - 4, xc, wxc), W1 = ldH(i0 - 3, xc, wxc),
          W2 = ldH(i0 - 2, xc, wxc), W3 = ldH(i0 - 1, xc, wxc),
          W4 = ldH(i0,     xc, wxc), W5 = ldH(i0 + 1, xc, wxc),
          W6 = ldH(i0 + 2, xc, wxc), W7 = ldH(i0 + 3, xc, wxc),
          W8 = ldH(i0 + 4, xc, wxc);

    const int xvbase = (i0 - rlo) * Wc + j;

#pragma unroll
    for (int r = 0; r < R; ++r) {
        float acc = cA[0] * S0 + cA[1] * S1 + cA[2] * S2
                  + cB[0] * W0 + cB[1] * W1 + cB[2] * W2
                  + cB[3] * W3 + cB[4] * W4 + cB[5] * W5
                  + cB[6] * W6 + cB[7] * W7 + cB[8] * W8;
        const float xv = tile[xvbase + (r << 8)];
        dst[(size_t)(r << 8)] = 0.25f * acc + tc * xv;
        if (r < R - 1) {
            S0 = S1; S1 = S2; S2 = ldS(i0 + r + 2);
            W0 = W1; W1 = W2; W2 = W3; W3 = W4; W4 = W5;
            W5 = W6; W6 = W7; W7 = W8; W8 = ldH(i0 + r + 5, xc, wxc);
        }
    }

    // ---- exact fixup for non-conforming rows (borders / rare floor flips) ----
    if (mask != 0xFFFFFFFFu) {
        for (int r = 0; r < R; ++r) {
            if ((mask >> r) & 1u) continue;
            const float gyr = gy_of(i0 + r);
            int yc, yp, yn; float wyc, wyp, wyn;
            coord_adj(gyr,      dy, Hc, yc, wyc);
            coord_adj(gyr,  s + dy, Hc, yp, wyp);
            coord_adj(gyr, -s + dy, Hc, yn, wyn);
            float v01 = (1.0f - wyc) * ldS(yc) + wyc * ldS(yc + 1);
            float v2  = (1.0f - wyp) * ldH(yp,     xc, wxc)
                      +         wyp  * ldH(yp + 1, xc, wxc);
            float v3  = (1.0f - wyn) * ldH(yn,     xc, wxc)
                      +         wyn  * ldH(yn + 1, xc, wxc);
            const float xv = tile[xvbase + (r << 8)];
            dst[(size_t)(r << 8)] = 0.25f * (v01 + v2 + v3) + tc * xv;
        }
    }
}

extern "C" void kernel_launch(void* const* d_in, const int* in_sizes, int n_in,
                              void* d_out, int out_size, void* d_ws, size_t ws_size,
                              hipStream_t stream)
{
    const float* x       = (const float*)d_in[0];
    const float* th_a    = (const float*)d_in[1];
    const float* th_bx   = (const float*)d_in[2];
    const float* th_by   = (const float*)d_in[3];
    const float* th_c    = (const float*)d_in[4];
    const float* base_gx = (const float*)d_in[5];
    const float* base_gy = (const float*)d_in[6];
    float* out = (float*)d_out;

    dim3 grid(Hc / R, Cc, Bc);
    dim3 block(Wc);
    remizov_sten<<<grid, block, 0, stream>>>(x, th_a, th_bx, th_by, th_c,
                                             base_gx, base_gy, out);
}